// Round 6
// baseline (1450.549 us; speedup 1.0000x reference)
//
#include <hip/hip_runtime.h>
#include <math.h>

// ---------------------------------------------------------------------------
// ConvLSTM stack, time-skewed pipeline, round 6.
//
// Round-5 (1179 us, best): dense role first (longest-latency), conv roles
// round-1 structure. ~34 us/stage vs ~20 us issue floor -> slack is stage
// boundaries + ramp/drain, so this round cuts STAGES, not work:
//
// Pool fusion via atomics: producers write pooled buffers directly
// (atomic fmax per 2x2 cell) as they produce h. Pool roles removed,
// skew 8 -> 4, NSTAGES 32 -> 28, launches 34 -> 30. Pool buffers are
// initialized to -inf by a fill kernel up front. Atomic fmax uses the
// sign-split int-atomic trick (exact, no float-atomic codegen risk).
//
// Roles per stage s (28 stages), in bid order (longest first):
//   r0: dense ch=s-4 ( 32 blk)    r3: L1 step t=s   ( 993 blk)
//   r1: L4 step t=s-3 ( 85 blk)   r4: L2 step t=s-1 (1861 blk)
//   r2: L3 step t=s-2 (421 blk)
// ---------------------------------------------------------------------------

static __device__ __forceinline__ float hsig(float x) {
    return fminf(fmaxf(fmaf(0.2f, x, 0.5f), 0.0f), 1.0f);
}
static __device__ __forceinline__ float ftanh(float x) {
    float e = __builtin_amdgcn_exp2f(x * 2.88539008177792681f);
    return 1.0f - 2.0f * __builtin_amdgcn_rcpf(e + 1.0f);
}

// Exact atomic fmax on float via int atomics (init must be -inf).
// Signed-int max works for v>=0 (and any stored value); unsigned-int min
// works for v<0 (keeps positives, picks largest float among negatives).
static __device__ __forceinline__ void atomic_fmax(float* a, float v) {
    if (__float_as_uint(v) == 0x80000000u) v = 0.0f;   // -0.0 -> +0.0
    if (v >= 0.0f) atomicMax((int*)a, __float_as_int(v));
    else           atomicMin((unsigned int*)a, __float_as_uint(v));
}

// ---- workspace layout (float offsets) ----
constexpr int H1SL = 32 * 126 * 126 * 4;   // 2,032,128
constexpr int H2SL = 32 * 61 * 61 * 8;     //   952,576
constexpr int H3SL = 32 * 29 * 29 * 12;    //   322,944
constexpr int H4SL = 32 * 13 * 13 * 16;    //    86,528
constexpr size_t O_H1 = 0;
constexpr size_t O_H2 = O_H1 + 2 * (size_t)H1SL;
constexpr size_t O_H3 = O_H2 + 2 * (size_t)H2SL;
constexpr size_t O_H4 = O_H3 + 2 * (size_t)H3SL;
constexpr size_t O_C1 = O_H4 + 2 * (size_t)H4SL;
constexpr size_t O_C2 = O_C1 + (size_t)H1SL;
constexpr size_t O_C3 = O_C2 + (size_t)H2SL;
constexpr size_t O_C4 = O_C3 + (size_t)H3SL;
constexpr size_t O_P1 = O_C4 + (size_t)H4SL;
constexpr size_t O_P2 = O_P1 + (size_t)(768 * 63 * 63 * 4);
constexpr size_t O_P3 = O_P2 + (size_t)(768 * 31 * 31 * 8);
constexpr size_t O_P4 = O_P3 + (size_t)(768 * 15 * 15 * 12);
constexpr size_t O_DP = O_P4 + (size_t)(768 * 7 * 7 * 16);
constexpr size_t NPOOLF = O_DP - O_P1;     // 20,772,864 floats (div by 4)

__host__ __device__ static inline int role_blocks(int r, int s) {
    int t;
    switch (r) {
    case 0: t = s - 4; return (t >= 0 && t < 24) ? 32   : 0;  // dense chunk
    case 1: t = s - 3; return (t >= 0 && t < 24) ? 85   : 0;  // L4 step
    case 2: t = s - 2; return (t >= 0 && t < 24) ? 421  : 0;  // L3 step
    case 3: t = s;     return (t >= 0 && t < 24) ? 993  : 0;  // L1 step
    case 4: t = s - 1; return (t >= 0 && t < 24) ? 1861 : 0;  // L2 step
    }
    return 0;
}
constexpr int NSTAGES = 28;

// ---- init pool buffers to -inf (pool cells are atomic-fmax targets) ----
__global__ __launch_bounds__(256)
void init_pools_k(float* __restrict__ p)
{
    const size_t stride = (size_t)gridDim.x * 256 * 4;
    for (size_t i = ((size_t)blockIdx.x * 256 + threadIdx.x) * 4;
         i + 3 < NPOOLF; i += stride)
        *reinterpret_cast<float4*>(p + i) =
            make_float4(-INFINITY, -INFINITY, -INFINITY, -INFINITY);
}

// ---- L1: merged gates, TWO adjacent pixels (same row) per thread ----
// Thread owns a full horizontal pool pair -> pre-reduce, 1 atomic/channel.
__device__ __forceinline__
void step_pair_d(const float* __restrict__ P,     // (B,T,128,128,3)
                 const float* __restrict__ Wx,    // (3,3,3,16)
                 const float* __restrict__ Wh,    // (3,3,4,16)
                 const float* __restrict__ bias,  // (16)
                 const float* __restrict__ h_prev,// (B,126,126,4) slice
                 float* __restrict__ h_cur,       // (B,126,126,4) slice
                 float* __restrict__ cbuf,        // (B,126,126,4)
                 float* __restrict__ pool,        // (B,T,63,63,4)
                 int t, int lb)
{
    constexpr int CIN = 3, F = 4, HIN = 128, WIN = 128;
    constexpr int B = 32, T = 24, HO = 126, WO = 126, G = 16;
    constexpr int XP = WO / 2;
    constexpr int NPAIR = B * HO * XP;
    const int id = lb * 256 + (int)threadIdx.x;
    if (id >= NPAIR) return;
    const int xp = id % XP;
    const int yy = (id / XP) % HO;
    const int b  = id / (XP * HO);
    const int x0 = 2 * xp;

    float acc[2][4][F];
    #pragma unroll
    for (int u = 0; u < 2; ++u)
        #pragma unroll
        for (int g = 0; g < 4; ++g)
            #pragma unroll
            for (int f = 0; f < F; ++f)
                acc[u][g][f] = bias[g * F + f];

    const float* Pt = P + (size_t)(b * T + t) * HIN * WIN * CIN;
    #pragma unroll
    for (int ky = 0; ky < 3; ++ky) {
        const float* prow = Pt + ((size_t)(yy + ky) * WIN + x0) * CIN;
        float pv[4 * CIN];
        #pragma unroll
        for (int j = 0; j < 2 * CIN; ++j) {
            float2 v2 = reinterpret_cast<const float2*>(prow)[j];
            pv[2 * j] = v2.x; pv[2 * j + 1] = v2.y;
        }
        #pragma unroll
        for (int dx = 0; dx < 4; ++dx)
            #pragma unroll
            for (int ci = 0; ci < CIN; ++ci) {
                const float v = pv[dx * CIN + ci];
                #pragma unroll
                for (int u = 0; u < 2; ++u) {
                    const int kx = dx - u;
                    if (kx >= 0 && kx <= 2) {
                        const float* wr =
                            Wx + (size_t)((ky * 3 + kx) * CIN + ci) * G;
                        #pragma unroll
                        for (int g = 0; g < 4; ++g)
                            #pragma unroll
                            for (int f = 0; f < F; ++f)
                                acc[u][g][f] = fmaf(v, wr[g * F + f], acc[u][g][f]);
                    }
                }
            }
    }

    if (t > 0) {
        #pragma unroll
        for (int ky = 0; ky < 3; ++ky) {
            const int hy = yy + ky - 1;
            if (hy < 0 || hy >= HO) continue;
            const float* hrow = h_prev + ((size_t)b * HO + hy) * WO * F;
            #pragma unroll
            for (int dx = 0; dx < 4; ++dx) {
                const int hx = x0 - 1 + dx;
                if (dx == 0 && x0 == 0) continue;
                if (dx == 3 && hx >= WO) continue;
                const float4* h4 =
                    reinterpret_cast<const float4*>(hrow + (size_t)hx * F);
                float hv[F];
                #pragma unroll
                for (int j = 0; j < F / 4; ++j) {
                    float4 v4 = h4[j];
                    hv[4*j] = v4.x; hv[4*j+1] = v4.y;
                    hv[4*j+2] = v4.z; hv[4*j+3] = v4.w;
                }
                #pragma unroll
                for (int ci = 0; ci < F; ++ci) {
                    const float v = hv[ci];
                    #pragma unroll
                    for (int u = 0; u < 2; ++u) {
                        const int kx = dx - u;
                        if (kx >= 0 && kx <= 2) {
                            const float* wr =
                                Wh + (size_t)((ky * 3 + kx) * F + ci) * G;
                            #pragma unroll
                            for (int g = 0; g < 4; ++g)
                                #pragma unroll
                                for (int f = 0; f < F; ++f)
                                    acc[u][g][f] =
                                        fmaf(v, wr[g * F + f], acc[u][g][f]);
                        }
                    }
                }
            }
        }
    }

    float hov[2][F];
    #pragma unroll
    for (int u = 0; u < 2; ++u) {
        const size_t pix = ((size_t)b * HO + yy) * WO + (x0 + u);
        float cn[F];
        float* cp = cbuf + pix * F;
        #pragma unroll
        for (int j = 0; j < F / 4; ++j) {
            float4 c4 = (t > 0) ? reinterpret_cast<float4*>(cp)[j]
                                : make_float4(0.f, 0.f, 0.f, 0.f);
            float cold[4] = {c4.x, c4.y, c4.z, c4.w};
            #pragma unroll
            for (int v = 0; v < 4; ++v) {
                const int f = 4 * j + v;
                const float ig = hsig(acc[u][0][f]), fg = hsig(acc[u][1][f]);
                const float cc = ftanh(acc[u][2][f]), og = hsig(acc[u][3][f]);
                cn[f] = fmaf(fg, cold[v], ig * cc);
                hov[u][f] = og * ftanh(cn[f]);
            }
            reinterpret_cast<float4*>(cp)[j] =
                make_float4(cn[4*j], cn[4*j+1], cn[4*j+2], cn[4*j+3]);
        }
        float* hp = h_cur + pix * F;
        #pragma unroll
        for (int j = 0; j < F / 4; ++j)
            reinterpret_cast<float4*>(hp)[j] =
                make_float4(hov[u][4*j], hov[u][4*j+1], hov[u][4*j+2], hov[u][4*j+3]);
    }

    // pooled write: cell (yy>>1, xp), horizontal pair pre-reduced
    float* pc = pool + (((size_t)(b * T + t) * 63 + (yy >> 1)) * 63 + xp) * F;
    #pragma unroll
    for (int f = 0; f < F; ++f)
        atomic_fmax(pc + f, fmaxf(hov[0][f], hov[1][f]));
}

// ---- gate-split step (L2/L3/L4): wave w = gate w of 64 pixels ----
template<int CIN, int F, int HIN, int WIN>
__device__ __forceinline__
void step_split_d(const float* __restrict__ P,     // (B,T,HIN,WIN,CIN) pooled
                  const float* __restrict__ Wx,
                  const float* __restrict__ Wh,
                  const float* __restrict__ bias,
                  const float* __restrict__ h_prev,// (B,HO,WO,F) slice
                  float* __restrict__ h_cur,
                  float* __restrict__ cbuf,
                  float* __restrict__ pool,        // (B,T,HP,WP,F)
                  int t, int lb, float* __restrict__ gb)
{
    constexpr int B = 32, T = 24, HO = HIN - 2, WO = WIN - 2, G = 4 * F;
    constexpr int HP = (HO + 1) / 2, WP = (WO + 1) / 2;
    constexpr int NPIX = B * HO * WO;
    const int tid = (int)threadIdx.x, lane = tid & 63;
    const int w = __builtin_amdgcn_readfirstlane(tid >> 6);
    const int pix = lb * 64 + lane;
    const int pp  = (pix < NPIX) ? pix : NPIX - 1;
    const int sp  = pp % (HO * WO);
    const int b   = pp / (HO * WO);
    const int xx  = sp % WO, yy = sp / WO;

    float acc[F];
    #pragma unroll
    for (int f = 0; f < F; ++f) acc[f] = bias[w * F + f];

    const float* Pt = P + (size_t)(b * T + t) * HIN * WIN * CIN;
    #pragma unroll
    for (int ky = 0; ky < 3; ++ky) {
        #pragma unroll
        for (int kx = 0; kx < 3; ++kx) {
            const float* prow = Pt + ((size_t)(yy + ky) * WIN + (xx + kx)) * CIN;
            float pv[CIN];
            #pragma unroll
            for (int j = 0; j < CIN / 4; ++j) {
                float4 v4 = reinterpret_cast<const float4*>(prow)[j];
                pv[4*j] = v4.x; pv[4*j+1] = v4.y; pv[4*j+2] = v4.z; pv[4*j+3] = v4.w;
            }
            #pragma unroll
            for (int ci = 0; ci < CIN; ++ci) {
                const float v = pv[ci];
                const float* wr = Wx + (size_t)((ky * 3 + kx) * CIN + ci) * G + w * F;
                #pragma unroll
                for (int f = 0; f < F; ++f)
                    acc[f] = fmaf(v, wr[f], acc[f]);
            }
        }
    }

    if (t > 0) {
        const float* Hp = h_prev + (size_t)b * HO * WO * F;
        #pragma unroll
        for (int ky = 0; ky < 3; ++ky) {
            const int hy = yy + ky - 1;
            if (hy < 0 || hy >= HO) continue;
            #pragma unroll
            for (int kx = 0; kx < 3; ++kx) {
                const int hx = xx + kx - 1;
                if (hx < 0 || hx >= WO) continue;
                const float4* h4 = reinterpret_cast<const float4*>(
                    Hp + ((size_t)hy * WO + hx) * F);
                float hv[F];
                #pragma unroll
                for (int j = 0; j < F / 4; ++j) {
                    float4 v4 = h4[j];
                    hv[4*j] = v4.x; hv[4*j+1] = v4.y; hv[4*j+2] = v4.z; hv[4*j+3] = v4.w;
                }
                #pragma unroll
                for (int ci = 0; ci < F; ++ci) {
                    const float v = hv[ci];
                    const float* wr = Wh + (size_t)((ky * 3 + kx) * F + ci) * G + w * F;
                    #pragma unroll
                    for (int f = 0; f < F; ++f)
                        acc[f] = fmaf(v, wr[f], acc[f]);
                }
            }
        }
    }

    #pragma unroll
    for (int f = 0; f < F; ++f) gb[w * (64 * F) + lane * F + f] = acc[f];
    __syncthreads();

    #pragma unroll
    for (int r2 = 0; r2 < F / 4; ++r2) {
        const int it = r2 * 256 + tid;
        const int pl = it / F, fo = it % F;
        const int pix2 = lb * 64 + pl;
        if (pix2 < NPIX) {
            const float ig = hsig(gb[0 * (64*F) + it]), fg = hsig(gb[1 * (64*F) + it]);
            const float cc = ftanh(gb[2 * (64*F) + it]), og = hsig(gb[3 * (64*F) + it]);
            const size_t cix = (size_t)pix2 * F + fo;
            const float cold = (t > 0) ? cbuf[cix] : 0.0f;
            const float cnw = fmaf(fg, cold, ig * cc);
            cbuf[cix] = cnw;
            const float hval = og * ftanh(cnw);
            h_cur[cix] = hval;
            const int sp2 = pix2 % (HO * WO);
            const int b2  = pix2 / (HO * WO);
            const int xx2 = sp2 % WO, yy2 = sp2 / WO;
            atomic_fmax(pool + (((size_t)(b2 * T + t) * HP + (yy2 >> 1)) * WP
                                + (xx2 >> 1)) * F + fo, hval);
        }
    }
}

// ---- dense partial for one FLAT chunk (= ONE t-slice of pool4, 784 el) ----
__device__ __forceinline__
void dense_partial_d(const float* __restrict__ X, const float* __restrict__ Wd,
                     float* __restrict__ part, int ch, int lb,
                     float* __restrict__ red)
{
    constexpr int FLAT = 18816, K = 50, NC = 24, CHUNK = FLAT / NC; // 784
    const int b = lb;
    const int tid = (int)threadIdx.x, lane = tid & 63, wv = tid >> 6;
    const float* xp = X + (size_t)b * FLAT;
    const int i0 = ch * CHUNK + wv * (CHUNK / 4);   // 196 per wave
    float a0 = 0.f, a1 = 0.f, a2 = 0.f, a3 = 0.f;
    if (lane < K) {
        #pragma unroll 4
        for (int i = i0; i < i0 + CHUNK / 4; i += 4) {
            a0 = fmaf(xp[i + 0], Wd[(size_t)(i + 0) * K + lane], a0);
            a1 = fmaf(xp[i + 1], Wd[(size_t)(i + 1) * K + lane], a1);
            a2 = fmaf(xp[i + 2], Wd[(size_t)(i + 2) * K + lane], a2);
            a3 = fmaf(xp[i + 3], Wd[(size_t)(i + 3) * K + lane], a3);
        }
    }
    red[tid] = (a0 + a1) + (a2 + a3);
    __syncthreads();
    if (tid < 64 && lane < K)
        part[((size_t)b * NC + ch) * K + lane]
            = red[tid] + red[tid + 64] + red[tid + 128] + red[tid + 192];
}

// ---- pipeline stage dispatcher ----
__global__ __launch_bounds__(256)
void pipe_k(const float* __restrict__ x,
            const float* __restrict__ Wx1, const float* __restrict__ Wh1, const float* __restrict__ b1,
            const float* __restrict__ Wx2, const float* __restrict__ Wh2, const float* __restrict__ b2,
            const float* __restrict__ Wx3, const float* __restrict__ Wh3, const float* __restrict__ b3,
            const float* __restrict__ Wx4, const float* __restrict__ Wh4, const float* __restrict__ b4,
            const float* __restrict__ Wd,
            float* __restrict__ ws, int s)
{
    float* h1 = ws + O_H1;  float* h2 = ws + O_H2;
    float* h3 = ws + O_H3;  float* h4 = ws + O_H4;
    float* c1 = ws + O_C1;  float* c2 = ws + O_C2;
    float* c3 = ws + O_C3;  float* c4 = ws + O_C4;
    float* p1 = ws + O_P1;  float* p2 = ws + O_P2;
    float* p3 = ws + O_P3;  float* p4 = ws + O_P4;
    float* dp = ws + O_DP;

    __shared__ float gb[4 * 64 * 16];   // split gate buffer / dense reduction

    int bid = (int)blockIdx.x, r = 0, cum = 0;
    for (; r < 5; ++r) {
        int n = role_blocks(r, s);
        if (bid < cum + n) break;
        cum += n;
    }
    const int lb = bid - cum;

    switch (r) {
    case 0: { const int ch = s - 4;  // dense chunk (longest-latency: FIRST)
        dense_partial_d(p4, Wd, dp, ch, lb, gb); } break;
    case 1: { const int t = s - 3;   // L4
        step_split_d<12, 16, 15, 15>(p3, Wx4, Wh4, b4,
            h4 + ((t - 1) & 1) * (size_t)H4SL, h4 + (t & 1) * (size_t)H4SL,
            c4, p4, t, lb, gb); } break;
    case 2: { const int t = s - 2;   // L3
        step_split_d<8, 12, 31, 31>(p2, Wx3, Wh3, b3,
            h3 + ((t - 1) & 1) * (size_t)H3SL, h3 + (t & 1) * (size_t)H3SL,
            c3, p3, t, lb, gb); } break;
    case 3: { const int t = s;       // L1
        step_pair_d(x, Wx1, Wh1, b1,
            h1 + ((t - 1) & 1) * (size_t)H1SL, h1 + (t & 1) * (size_t)H1SL,
            c1, p1, t, lb); } break;
    case 4: { const int t = s - 1;   // L2
        step_split_d<4, 8, 63, 63>(p1, Wx2, Wh2, b2,
            h2 + ((t - 1) & 1) * (size_t)H2SL, h2 + (t & 1) * (size_t)H2SL,
            c2, p2, t, lb, gb); } break;
    }
}

__global__ __launch_bounds__(64)
void dense_finish_k(const float* __restrict__ part, const float* __restrict__ bd,
                    float* __restrict__ out)
{
    constexpr int K = 50, NC = 24;
    const int b = blockIdx.x, lane = threadIdx.x;
    float v = -INFINITY;
    if (lane < K) {
        v = bd[lane];
        #pragma unroll
        for (int c = 0; c < NC; ++c)
            v += part[((size_t)b * NC + c) * K + lane];
    }
    float m = v;
    #pragma unroll
    for (int off = 32; off > 0; off >>= 1) m = fmaxf(m, __shfl_xor(m, off));
    float e = (lane < K) ? __expf(v - m) : 0.0f;
    float sgm = e;
    #pragma unroll
    for (int off = 32; off > 0; off >>= 1) sgm += __shfl_xor(sgm, off);
    if (lane < K) out[(size_t)b * K + lane] = e / sgm;
}

extern "C" void kernel_launch(void* const* d_in, const int* in_sizes, int n_in,
                              void* d_out, int out_size, void* d_ws, size_t ws_size,
                              hipStream_t stream)
{
    const float* x   = (const float*)d_in[0];
    const float* Wx1 = (const float*)d_in[1];
    const float* Wh1 = (const float*)d_in[2];
    const float* b1  = (const float*)d_in[3];
    const float* Wx2 = (const float*)d_in[4];
    const float* Wh2 = (const float*)d_in[5];
    const float* b2  = (const float*)d_in[6];
    const float* Wx3 = (const float*)d_in[7];
    const float* Wh3 = (const float*)d_in[8];
    const float* b3  = (const float*)d_in[9];
    const float* Wx4 = (const float*)d_in[10];
    const float* Wh4 = (const float*)d_in[11];
    const float* b4  = (const float*)d_in[12];
    const float* Wd  = (const float*)d_in[13];
    const float* bd  = (const float*)d_in[14];
    float* out = (float*)d_out;
    float* ws  = (float*)d_ws;

    // pool buffers to -inf (atomic-fmax targets), ~83 MB
    init_pools_k<<<2048, 256, 0, stream>>>(ws + O_P1);

    for (int s = 0; s < NSTAGES; ++s) {
        int nb = 0;
        for (int r = 0; r < 5; ++r) nb += role_blocks(r, s);
        pipe_k<<<nb, 256, 0, stream>>>(x,
                                       Wx1, Wh1, b1, Wx2, Wh2, b2,
                                       Wx3, Wh3, b3, Wx4, Wh4, b4,
                                       Wd, ws, s);
    }
    dense_finish_k<<<32, 64, 0, stream>>>(ws + O_DP, bd, out);
}